// Round 7
// baseline (191.112 us; speedup 1.0000x reference)
//
#include <hip/hip_runtime.h>

#define EPSL 1e-9f
#define NGROUPS 638976                  // 8192 * 26 * 3 rows of 31 floats
#define NB 2496                         // blocks
#define ROWS_PER_BLOCK 8                // 256 threads / 32 lanes-per-row
#define RSTRIDE (NB * ROWS_PER_BLOCK)   // 19968 rows per grid step
#define NSTEPS (NGROUPS / RSTRIDE)      // 32 exactly, no remainder
#define UNROLL 4
#define NSLOTS 64                       // padded accumulator slots (64 B stride)

__global__ __launch_bounds__(256) void laneline_reduce_kernel(
    const float* __restrict__ pred,
    const float* __restrict__ gt,
    float* __restrict__ ws)             // NSLOTS slots of 16 floats
{
    const int tid  = threadIdx.x;
    const int lane = tid & 63;
    const int d    = tid & 31;          // position within the 31-float group
    const int dc   = (d < 31) ? d : 30; // clamp lane 31 (same line, masked to 0)

    // lane-constant bpermute byte-indices (wave-local source lane * 4)
    const int rowbase = lane & 32;                       // 0 or 32
    const int idxVis  = (rowbase + 20 + (d % 10)) * 4;   // gt_vis[d%10] of my row
    const int idxCls  = (rowbase + 30) * 4;              // gt_class of my row
    // lane-constant class masks (no divergence, no cndmask in loop)
    const float mA = (d < 20) ? 1.f : 0.f;
    const float mV = (d >= 20 && d < 30) ? 1.f : 0.f;
    const float mC = (d == 30) ? 1.f : 0.f;

    const int row0 = blockIdx.x * ROWS_PER_BLOCK + (tid >> 5);
    size_t base = (size_t)row0 * 31 + dc;
    const size_t stride = (size_t)RSTRIDE * 31;

    float a0 = 0.f, a1 = 0.f, a2 = 0.f;
#pragma unroll 1
    for (int s = 0; s < NSTEPS; s += UNROLL) {
        float pv[UNROLL], gv[UNROLL];
#pragma unroll
        for (int u = 0; u < UNROLL; ++u) {      // 8 full-exec loads, clause-able
            pv[u] = pred[base + (size_t)u * stride];
            gv[u] = gt[base + (size_t)u * stride];
        }
#pragma unroll
        for (int u = 0; u < UNROLL; ++u) {
            const float p = pv[u], g = gv[u];
            const float gvis = __int_as_float(
                __builtin_amdgcn_ds_bpermute(idxVis, __float_as_int(g)));
            const float gcls = __int_as_float(
                __builtin_amdgcn_ds_bpermute(idxCls, __float_as_int(g)));
            const float lp1 = __logf(p + EPSL);
            const float lp2 = __logf(1.0f - p + EPSL);
            // anchor L1 (gcls,gvis >= 0 -> |w*(p-g)| = w*|p-g|; absmax=0 R2-R6)
            a2 = fmaf(mA, gcls * gvis * fabsf(p - g), a2);
            // vis BCE: gt factor is this lane's own g
            a0 = fmaf(mV, fmaf(g, lp1, (1.0f - g + EPSL) * lp2), a0);
            // class BCE
            a1 = fmaf(mC, fmaf(g, lp1, (1.0f - g) * lp2), a1);
        }
        base += (size_t)UNROLL * stride;
    }

    // ---- wave(64) shuffle reduction ----
#pragma unroll
    for (int off = 32; off > 0; off >>= 1) {
        a0 += __shfl_down(a0, off, 64);
        a1 += __shfl_down(a1, off, 64);
        a2 += __shfl_down(a2, off, 64);
    }
    __shared__ float red[12];
    const int wid = tid >> 6;
    if (lane == 0) { red[wid] = a0; red[4 + wid] = a1; red[8 + wid] = a2; }
    __syncthreads();
    if (tid == 0) {
        float* slot = ws + (blockIdx.x & (NSLOTS - 1)) * 16;
        atomicAdd(&slot[0], red[0] + red[1] + red[2]  + red[3]);
        atomicAdd(&slot[1], red[4] + red[5] + red[6]  + red[7]);
        atomicAdd(&slot[2], red[8] + red[9] + red[10] + red[11]);
    }
}

__global__ __launch_bounds__(64) void laneline_finalize_kernel(
    const float* __restrict__ ws, float* __restrict__ out)
{
    const int t = threadIdx.x;
    float v0 = ws[t * 16], v1 = ws[t * 16 + 1], v2 = ws[t * 16 + 2];
#pragma unroll
    for (int off = 32; off > 0; off >>= 1) {
        v0 += __shfl_down(v0, off, 64);
        v1 += __shfl_down(v1, off, 64);
        v2 += __shfl_down(v2, off, 64);
    }
    if (t == 0) {
        const float l0 = -v0 * 0.1f;   // / NUM_Y_STEPS, negated
        const float l1 = -v1;
        const float l2 =  v2;
        out[0] = l0 + l1 + l2;
        out[1] = l0;
        out[2] = l1;
        out[3] = l2;
    }
}

extern "C" void kernel_launch(void* const* d_in, const int* in_sizes, int n_in,
                              void* d_out, int out_size, void* d_ws, size_t ws_size,
                              hipStream_t stream)
{
    const float* pred = (const float*)d_in[0];
    const float* gt   = (const float*)d_in[1];
    // d_in[2..5] (hcam/pitch) are unused by the reference computation.
    float* ws  = (float*)d_ws;
    float* out = (float*)d_out;

    hipMemsetAsync(ws, 0, NSLOTS * 16 * sizeof(float), stream);

    laneline_reduce_kernel<<<NB, 256, 0, stream>>>(pred, gt, ws);
    laneline_finalize_kernel<<<1, 64, 0, stream>>>(ws, out);
}